// Round 9
// baseline (137.261 us; speedup 1.0000x reference)
//
#include <hip/hip_runtime.h>
#include <stdint.h>

#define M_TOTAL 16384
#define N_TOTAL 1024
#define K_TOTAL 1024
#define BM 256
#define BN 256
#define BK 64
#define NTILES (K_TOTAL / BK)       // 16
#define NWG ((M_TOTAL / BM) * (N_TOTAL / BN))   // 256

using f32x4  = __attribute__((ext_vector_type(4))) float;
using bf16x8 = __attribute__((ext_vector_type(8))) short;
using bf16x4 = __attribute__((ext_vector_type(4))) short;

#define AS1 __attribute__((address_space(1)))
#define AS3 __attribute__((address_space(3)))
#define SB() __builtin_amdgcn_sched_barrier(0)

__device__ __forceinline__ unsigned packrne(float x, float y) {
    unsigned ux = __builtin_bit_cast(unsigned, x);
    unsigned uy = __builtin_bit_cast(unsigned, y);
    ux += 0x7fffu + ((ux >> 16) & 1u);
    uy += 0x7fffu + ((uy >> 16) & 1u);
    return (ux >> 16) | (uy & 0xffff0000u);
}

// ---------------- kernel 1: W fp32 -> bf16 (4 MB read / 2 MB write) ---------
#define N8W (N_TOTAL * K_TOTAL / 8)   // 131072
__global__ __launch_bounds__(256) void cvtW_kernel(
    const float* __restrict__ W, uint4* __restrict__ Wb)
{
    const int i = blockIdx.x * 256 + threadIdx.x;
    const f32x4* p = (const f32x4*)W + (size_t)i * 2;
    const f32x4 a = p[0], b = p[1];
    uint4 r;
    r.x = packrne(a[0], a[1]);
    r.y = packrne(a[2], a[3]);
    r.z = packrne(b[0], b[1]);
    r.w = packrne(b[2], b[3]);
    Wb[i] = r;
}

// ---------------- kernel 2: r4 skeleton + in-kernel A conversion ------------
// C[m][n] = sum_k X[m][k]*W[n][k] + bias[n].  256x256 tile, 8 waves (2Mx4N,
// wave-tile 128x64), BK=64, LDS 128KB dbuf.  Per tile:
//   B1 barrier -> write_A(buf^1, A(t+1) regs)  [compiler's reg-wait = counted
//   vmcnt: A(t+1) newer than B(t)'s gloads -> retires B(t), >=1 tile old]
//   -> stage_B(t+1, buf^1) gload_lds x4 -> lgkm0 -> B2 barrier ->
//   compute 4 quadrant phases on buf (issues load_A(t+2) up front).
// A LDS layout: row r (128B, 64 k-elems), 16B slot s holds kg = s ^ (r&7).
// B LDS: identical map via linear gload_lds dest + pre-swizzled source (r4).
__global__ __launch_bounds__(512) void gemm8f_kernel(
    const float* __restrict__ X, const unsigned short* __restrict__ Wb,
    const float* __restrict__ bias, float* __restrict__ C)
{
    __shared__ __align__(16) char smem[131072]; // A0@0 A1@32768 B0@65536 B1@98304

    const int tid  = threadIdx.x;
    const int lane = tid & 63;
    const int wave = tid >> 6;      // 0..7
    const int wr = wave >> 2;       // 0..1 : 128-row strip
    const int wc = wave & 3;        // 0..3 : 64-col strip

    // XCD-chunked swizzle (verified r2-r8)
    const int bid  = blockIdx.x;
    const int work = (bid & 7) * (NWG / 8) + (bid >> 3);
    const int bm = work >> 2;
    const int bn = work & 3;
    const int m0 = bm * BM, n0 = bn * BN;

    // ---- B staging: gload_lds, linear dest + pre-swizzled source (r4) ------
    const int srow64 = wave * 8 + (lane >> 3);
    const int kge    = ((lane & 7) ^ ((lane >> 3) & 7)) * 8;
    auto stage_B = [&](int t, int b) {
        #pragma unroll
        for (int j = 0; j < 4; ++j) {
            __builtin_amdgcn_global_load_lds(
                (const AS1 void*)(Wb + (size_t)(n0 + j * 64 + srow64) * K_TOTAL
                                     + t * BK + kge),
                (AS3 void*)(smem + 65536 + b * 32768 + j * 8192 + wave * 1024),
                16, 0, 0);
        }
    };

    // ---- A staging: fp32 reg-load (1.5 tiles early) + convert + ds_write ---
    const int arow = tid >> 1;      // 0..255
    const int ac   = tid & 1;       // which 32-k half of the row
    const int ars  = arow & 7;
    auto load_A = [&](int t, f32x4 (&v)[8]) {
        const f32x4* p = (const f32x4*)(X + (size_t)(m0 + arow) * K_TOTAL
                                          + t * BK + ac * 32);
        #pragma unroll
        for (int i = 0; i < 8; ++i) v[i] = p[i];
    };
    auto write_A = [&](int b, const f32x4 (&v)[8]) {
        #pragma unroll
        for (int j = 0; j < 4; ++j) {
            uint4 c;
            c.x = packrne(v[2 * j][0], v[2 * j][1]);
            c.y = packrne(v[2 * j][2], v[2 * j][3]);
            c.z = packrne(v[2 * j + 1][0], v[2 * j + 1][1]);
            c.w = packrne(v[2 * j + 1][2], v[2 * j + 1][3]);
            *(uint4*)(smem + b * 32768 + arow * 128
                      + (((ac * 4 + j) ^ ars) << 4)) = c;
        }
    };

    const int cl = lane & 15;
    const int kb = lane >> 4;       // 0..3

    f32x4 acc[8][4] = {};

#define BARRIER() SB(); __builtin_amdgcn_s_barrier(); SB()
#define LGKM0()   asm volatile("s_waitcnt lgkmcnt(0)" ::: "memory"); SB()
#define VM0()     asm volatile("s_waitcnt vmcnt(0)" ::: "memory"); SB()

    // ---- compute: r4's 4 quadrant phases, verbatim; loads A(t+2) up front --
    auto compute_tile = [&](int dbuf, f32x4 (&L)[8], bool doload, int tload) {
        if (doload) load_A(tload, L);
        const char* Abase = smem + dbuf * 32768;
        const char* Bbase = smem + 65536 + dbuf * 32768;
        bf16x8 aF[4][2], bF0[2][2], bF1[2][2];

        // phase 1: A rows 0-63 + B cols 0-31 ; MFMA Q(0,0)
        #pragma unroll
        for (int i = 0; i < 4; ++i) {
            const int ar = wr * 128 + i * 16 + cl;
            const int rs = ar & 7;
            aF[i][0] = *(const bf16x8*)(Abase + ar * 128 + ((kb       ^ rs) << 4));
            aF[i][1] = *(const bf16x8*)(Abase + ar * 128 + (((kb + 4) ^ rs) << 4));
        }
        #pragma unroll
        for (int j = 0; j < 2; ++j) {
            const int br = wc * 64 + j * 16 + cl;
            const int rs = br & 7;
            bF0[j][0] = *(const bf16x8*)(Bbase + br * 128 + ((kb       ^ rs) << 4));
            bF0[j][1] = *(const bf16x8*)(Bbase + br * 128 + (((kb + 4) ^ rs) << 4));
        }
        __builtin_amdgcn_s_setprio(1);
        #pragma unroll
        for (int i = 0; i < 4; ++i)
            #pragma unroll
            for (int j = 0; j < 2; ++j) {
                acc[i][j] = __builtin_amdgcn_mfma_f32_16x16x32_bf16(aF[i][0], bF0[j][0], acc[i][j], 0, 0, 0);
                acc[i][j] = __builtin_amdgcn_mfma_f32_16x16x32_bf16(aF[i][1], bF0[j][1], acc[i][j], 0, 0, 0);
            }
        __builtin_amdgcn_s_setprio(0);

        // phase 2: B cols 32-63 ; MFMA Q(0,1)
        #pragma unroll
        for (int j = 0; j < 2; ++j) {
            const int br = wc * 64 + 32 + j * 16 + cl;
            const int rs = br & 7;
            bF1[j][0] = *(const bf16x8*)(Bbase + br * 128 + ((kb       ^ rs) << 4));
            bF1[j][1] = *(const bf16x8*)(Bbase + br * 128 + (((kb + 4) ^ rs) << 4));
        }
        __builtin_amdgcn_s_setprio(1);
        #pragma unroll
        for (int i = 0; i < 4; ++i)
            #pragma unroll
            for (int j = 0; j < 2; ++j) {
                acc[i][2 + j] = __builtin_amdgcn_mfma_f32_16x16x32_bf16(aF[i][0], bF1[j][0], acc[i][2 + j], 0, 0, 0);
                acc[i][2 + j] = __builtin_amdgcn_mfma_f32_16x16x32_bf16(aF[i][1], bF1[j][1], acc[i][2 + j], 0, 0, 0);
            }
        __builtin_amdgcn_s_setprio(0);

        // phase 3: A rows 64-127 (reuse aF regs) ; MFMA Q(1,1)
        #pragma unroll
        for (int i = 0; i < 4; ++i) {
            const int ar = wr * 128 + 64 + i * 16 + cl;
            const int rs = ar & 7;
            aF[i][0] = *(const bf16x8*)(Abase + ar * 128 + ((kb       ^ rs) << 4));
            aF[i][1] = *(const bf16x8*)(Abase + ar * 128 + (((kb + 4) ^ rs) << 4));
        }
        __builtin_amdgcn_s_setprio(1);
        #pragma unroll
        for (int i = 0; i < 4; ++i)
            #pragma unroll
            for (int j = 0; j < 2; ++j) {
                acc[4 + i][2 + j] = __builtin_amdgcn_mfma_f32_16x16x32_bf16(aF[i][0], bF1[j][0], acc[4 + i][2 + j], 0, 0, 0);
                acc[4 + i][2 + j] = __builtin_amdgcn_mfma_f32_16x16x32_bf16(aF[i][1], bF1[j][1], acc[4 + i][2 + j], 0, 0, 0);
            }
        __builtin_amdgcn_s_setprio(0);

        // phase 4: MFMA Q(1,0) (all frags in regs)
        __builtin_amdgcn_s_setprio(1);
        #pragma unroll
        for (int i = 0; i < 4; ++i)
            #pragma unroll
            for (int j = 0; j < 2; ++j) {
                acc[4 + i][j] = __builtin_amdgcn_mfma_f32_16x16x32_bf16(aF[i][0], bF0[j][0], acc[4 + i][j], 0, 0, 0);
                acc[4 + i][j] = __builtin_amdgcn_mfma_f32_16x16x32_bf16(aF[i][1], bF0[j][1], acc[4 + i][j], 0, 0, 0);
            }
        __builtin_amdgcn_s_setprio(0);
    };

    // ---- prologue ----------------------------------------------------------
    // Order matters: B(0) issued BEFORE the A loads, so write_A's implicit
    // wait on aP (newer) also retires B(0) before the first barrier.
    f32x4 aP[8], aQ[8];
    stage_B(0, 0);
    load_A(0, aP);
    load_A(1, aQ);
    write_A(0, aP);     // waits aP -> drains B(0)+aP; aQ stays in flight
    LGKM0();

    // ---- main loop (2x unrolled for static reg ping-pong) ------------------
    #pragma unroll 1
    for (int t = 0; t < NTILES; t += 2) {
        // tile t (buf 0)
        BARRIER();                                   // B1: buf1 free
        write_A(1, aQ);                              // A(t+1); waits aQ -> retires B(t)
        stage_B(t + 1, 1);
        LGKM0();
        BARRIER();                                   // B2: tile t ready
        compute_tile(0, aP, t + 2 < NTILES, t + 2);  // loads A(t+2) -> aP

        // tile t+1 (buf 1)
        BARRIER();                                   // B1: buf0 free
        if (t + 2 < NTILES) {
            write_A(0, aP);                          // A(t+2); waits aP -> retires B(t+1)
            stage_B(t + 2, 0);
            LGKM0();
        } else {
            VM0();                                   // force B(t+1) for final tile
        }
        BARRIER();                                   // B2: tile t+1 ready
        compute_tile(1, aQ, t + 3 < NTILES, t + 3);  // loads A(t+3) -> aQ
    }

    // ---- epilogue: D element (row=(lane>>4)*4+r, col=lane&15) [m89] --------
    const int r0 = (lane >> 4) * 4;
    #pragma unroll
    for (int ni = 0; ni < 4; ++ni) {
        const int n = n0 + wc * 64 + ni * 16 + cl;
        const float bvv = bias[n];
        #pragma unroll
        for (int mi = 0; mi < 8; ++mi) {
            const int m = m0 + wr * 128 + mi * 16 + r0;
            #pragma unroll
            for (int r = 0; r < 4; ++r)
                C[(size_t)(m + r) * N_TOTAL + n] = acc[mi][ni][r] + bvv;
        }
    }
#undef BARRIER
#undef LGKM0
#undef VM0
}

// ---------------- fallback: round-1 single kernel (known-good) --------------
__device__ __forceinline__ short f2bf(float f) {
    unsigned u = __builtin_bit_cast(unsigned, f);
    u += 0x7fffu + ((u >> 16) & 1u);
    return (short)(u >> 16);
}

#define FBM 128
#define FBN 128
#define FNWG ((M_TOTAL / FBM) * (N_TOTAL / FBN))   // 1024

__global__ __launch_bounds__(256) void fb_gemm_bias_kernel(
    const float* __restrict__ X, const float* __restrict__ W,
    const float* __restrict__ bias, float* __restrict__ C)
{
    __shared__ short As[FBM * BK];
    __shared__ short Bs[FBN * BK];

    const int tid  = threadIdx.x;
    const int lane = tid & 63;
    const int wave = tid >> 6;
    const int wr = wave >> 1;
    const int wc = wave & 1;

    const int bid  = blockIdx.x;
    const int work = (bid & 7) * (FNWG / 8) + (bid >> 3);
    const int bm = work >> 3;
    const int bn = work & 7;
    const int m0 = bm * FBM, n0 = bn * FBN;

    const int srow  = tid >> 4;
    const int scol4 = tid & 15;

    f32x4 acc[4][4] = {};
    char* const Ab = (char*)As;
    char* const Bb = (char*)Bs;

    for (int k0 = 0; k0 < K_TOTAL; k0 += BK) {
        __syncthreads();
        #pragma unroll
        for (int pass = 0; pass < 8; ++pass) {
            const int row = srow + pass * 16;
            const int off = (row * (BK * 2) + scol4 * 8) ^ ((row & 7) << 4);
            {
                const f32x4 v = *(const f32x4*)(X + (size_t)(m0 + row) * K_TOTAL + k0 + scol4 * 4);
                bf16x4 b;
                b[0] = f2bf(v[0]); b[1] = f2bf(v[1]); b[2] = f2bf(v[2]); b[3] = f2bf(v[3]);
                *(bf16x4*)(Ab + off) = b;
            }
            {
                const f32x4 v = *(const f32x4*)(W + (size_t)(n0 + row) * K_TOTAL + k0 + scol4 * 4);
                bf16x4 b;
                b[0] = f2bf(v[0]); b[1] = f2bf(v[1]); b[2] = f2bf(v[2]); b[3] = f2bf(v[3]);
                *(bf16x4*)(Bb + off) = b;
            }
        }
        __syncthreads();

        #pragma unroll
        for (int ks = 0; ks < 2; ++ks) {
            const int kel = ks * 32 + ((lane >> 4) << 3);
            bf16x8 af[4], bfr[4];
            #pragma unroll
            for (int i = 0; i < 4; ++i) {
                const int ar = wr * 64 + i * 16 + (lane & 15);
                af[i]  = *(const bf16x8*)(Ab + ((ar * (BK * 2) + kel * 2) ^ ((ar & 7) << 4)));
                const int br = wc * 64 + i * 16 + (lane & 15);
                bfr[i] = *(const bf16x8*)(Bb + ((br * (BK * 2) + kel * 2) ^ ((br & 7) << 4)));
            }
            #pragma unroll
            for (int mi = 0; mi < 4; ++mi)
                #pragma unroll
                for (int ni = 0; ni < 4; ++ni)
                    acc[mi][ni] = __builtin_amdgcn_mfma_f32_16x16x32_bf16(
                        af[mi], bfr[ni], acc[mi][ni], 0, 0, 0);
        }
    }

    const int cl = lane & 15;
    const int r0 = (lane >> 4) * 4;
    #pragma unroll
    for (int ni = 0; ni < 4; ++ni) {
        const int n = n0 + wc * 64 + ni * 16 + cl;
        const float bvv = bias[n];
        #pragma unroll
        for (int mi = 0; mi < 4; ++mi) {
            const int m = m0 + wr * 64 + mi * 16 + r0;
            #pragma unroll
            for (int r = 0; r < 4; ++r)
                C[(size_t)(m + r) * N_TOTAL + n] = acc[mi][ni][r] + bvv;
        }
    }
}

extern "C" void kernel_launch(void* const* d_in, const int* in_sizes, int n_in,
                              void* d_out, int out_size, void* d_ws, size_t ws_size,
                              hipStream_t stream) {
    // inputs: 0:X 1:Wq 2:bq 3:Wk 4:bk 5:Wv 6:bv
    // softmax rows sum to 1 => out = X @ Wv^T + bv exactly.
    const float* X  = (const float*)d_in[0];
    const float* Wv = (const float*)d_in[5];
    const float* bv = (const float*)d_in[6];
    float* out = (float*)d_out;

    const size_t WB_BYTES = (size_t)N_TOTAL * K_TOTAL * 2;   // 2 MiB

    if (ws_size >= WB_BYTES) {
        unsigned short* Wb = (unsigned short*)d_ws;
        cvtW_kernel<<<dim3(N8W / 256), dim3(256), 0, stream>>>(Wv, (uint4*)Wb);
        gemm8f_kernel<<<dim3(NWG), dim3(512), 0, stream>>>(X, Wb, bv, out);
    } else {
        fb_gemm_bias_kernel<<<dim3(FNWG), dim3(256), 0, stream>>>(X, Wv, bv, out);
    }
}